// Round 5
// baseline (463.606 us; speedup 1.0000x reference)
//
#include <hip/hip_runtime.h>
#include <hip/hip_bf16.h>

using bf16 = __hip_bfloat16;
typedef __attribute__((ext_vector_type(8))) short short8;   // 8 x bf16 fragment (4 VGPRs)
typedef __attribute__((ext_vector_type(4))) float f32x4;
typedef unsigned long long ull;

static constexpr int SEQ  = 2048;
static constexpr int HID  = 3072;
static constexpr int NH   = 24;
static constexpr int HD   = 128;
static constexpr int QKVN = 9216;

__device__ __forceinline__ f32x4 mfma_16x16x32(short8 a, short8 b, f32x4 c) {
  return __builtin_amdgcn_mfma_f32_16x16x32_bf16(a, b, c, 0, 0, 0);
}

#define GLOAD_LDS16(g, l) __builtin_amdgcn_global_load_lds(                 \
    (const __attribute__((address_space(1))) void*)(g),                    \
    (__attribute__((address_space(3))) void*)(l), 16, 0, 0)

typedef __attribute__((address_space(3))) const unsigned char lds_cchar;

// ---------------- fp32 -> bf16 vectorized convert ----------------
__global__ __launch_bounds__(256)
void cvt_f32_bf16_vec(const float* __restrict__ src, bf16* __restrict__ dst, int n4) {
  int i = blockIdx.x * 256 + threadIdx.x;
  if (i >= n4) return;
  float4 v = ((const float4*)src)[i];
  ushort4 o;
  bf16 t0 = __float2bfloat16(v.x); o.x = *(unsigned short*)&t0;
  bf16 t1 = __float2bfloat16(v.y); o.y = *(unsigned short*)&t1;
  bf16 t2 = __float2bfloat16(v.z); o.z = *(unsigned short*)&t2;
  bf16 t3 = __float2bfloat16(v.w); o.w = *(unsigned short*)&t3;
  ((ushort4*)dst)[i] = o;
}

// ---------------- fp32 (R x C) -> bf16 transposed (C x R) ----------------
__global__ __launch_bounds__(256)
void transpose_cvt(const float* __restrict__ src, bf16* __restrict__ dst, int R, int C) {
  __shared__ float tile[32][33];
  const int c0 = blockIdx.x * 32, r0 = blockIdx.y * 32;
  const int tc = threadIdx.x & 31, tr = threadIdx.x >> 5;
  #pragma unroll
  for (int i = 0; i < 4; ++i)
    tile[tr + i * 8][tc] = src[(long)(r0 + tr + i * 8) * C + c0 + tc];
  __syncthreads();
  #pragma unroll
  for (int i = 0; i < 4; ++i)
    dst[(long)(c0 + tr + i * 8) * R + r0 + tc] = __float2bfloat16(tile[tc][tr + i * 8]);
}

// ---------------- GEMM1: 256x256 tile, dbuf-2, burst-stage, 1 barrier/K-tile ----------------
// 8 waves (2M x 4N), per-wave 128x64. Per K-tile per wave: 24 ds_read_b128 (minimal:
// A halves read once via quadrant order Q00->Q01->Q11->Q10, B n0-1 held whole tile).
// All 8 global_load_lds for tile t+1 burst-issued at tile start into the opposite
// buffer (consumed last tile -> race-free); single vmcnt(0)+barrier per K-tile, by
// which point loads are ~2300 cyc old (drain ~free). T2 swizzle as in r4 (verified).
template<int BIAS, int OUTF32>
__global__ __launch_bounds__(512, 2)
void gemm256v2(const bf16* __restrict__ A, const bf16* __restrict__ BT,
               const float* __restrict__ bias, void* __restrict__ Cout,
               int M, int N, int K, int nbm) {
  __shared__ __align__(16) bf16 Asb[2][256 * 64];
  __shared__ __align__(16) bf16 Bsb[2][256 * 64];

  const int tid  = threadIdx.x;
  const int lane = tid & 63;
  const int wid  = tid >> 6;
  const int wm   = wid & 1;     // M half (128 rows)
  const int wn   = wid >> 1;    // N quarter (64 cols)
  const int lr   = lane & 15;
  const int lg   = lane >> 4;

  // bm fastest: 8 consecutive blocks (one per XCD) share the same B panel via L3.
  const int bm = (blockIdx.x % nbm) * 256;
  const int bn = (blockIdx.x / nbm) * 256;

  // staging: each instr covers 64 rows x 64 k (8 KB = 512 thr x 16 B)
  const int rl   = wid * 8 + (lane >> 3);                  // row 0..63 within block
  const int csrc = ((lane & 7) ^ ((lane >> 3) & 7)) * 8;   // pre-swizzled source chunk
  const bf16* Ag = A  + (size_t)(bm + rl) * K + csrc;
  const bf16* Bg = BT + (size_t)(bn + rl) * K + csrc;

#define STAGE_A(b, u, j) GLOAD_LDS16(Ag + (size_t)((j) * 64) * K + (u) * 64,  \
                                     Asb[b] + ((j) * 64 + wid * 8) * 64)
#define STAGE_B(b, u, j) GLOAD_LDS16(Bg + (size_t)((j) * 64) * K + (u) * 64,  \
                                     Bsb[b] + ((j) * 64 + wid * 8) * 64)
#define RD_A(b, m, kk) (*(const short8*)(Asb[b] + (wm * 128 + (m) * 16 + lr) * 64 \
                          + ((((kk) * 4 + lg) ^ (lr & 7)) * 8)))
#define RD_B(b, n, kk) (*(const short8*)(Bsb[b] + (wn * 64 + (n) * 16 + lr) * 64 \
                          + ((((kk) * 4 + lg) ^ (lr & 7)) * 8)))

  f32x4 acc[8][4] = {};
  const int NT = K >> 6;

  // prologue: stage tile 0 into buf0
  #pragma unroll
  for (int j = 0; j < 4; ++j) STAGE_A(0, 0, j);
  #pragma unroll
  for (int j = 0; j < 4; ++j) STAGE_B(0, 0, j);
  asm volatile("s_waitcnt vmcnt(0)" ::: "memory");
  __builtin_amdgcn_s_barrier();

  for (int t = 0; t < NT; ++t) {
    const int c = t & 1, nc = c ^ 1;
    const bool pf = (t + 1) < NT;

    // burst-stage tile t+1 (8 instrs) first, so the end-of-tile drain is ~free
    if (pf) {
      STAGE_A(nc, t + 1, 0); STAGE_A(nc, t + 1, 1);
      STAGE_A(nc, t + 1, 2); STAGE_A(nc, t + 1, 3);
      STAGE_B(nc, t + 1, 0); STAGE_B(nc, t + 1, 1);
      STAGE_B(nc, t + 1, 2); STAGE_B(nc, t + 1, 3);
    }
    __builtin_amdgcn_sched_barrier(0);

    // ---- Q00: A m0-3 (8 reads) + B n0-1 (4 reads, held whole tile)
    short8 a0 = RD_A(c, 0, 0), a1 = RD_A(c, 1, 0), a2 = RD_A(c, 2, 0), a3 = RD_A(c, 3, 0);
    short8 a4 = RD_A(c, 0, 1), a5 = RD_A(c, 1, 1), a6 = RD_A(c, 2, 1), a7 = RD_A(c, 3, 1);
    short8 b0 = RD_B(c, 0, 0), b1 = RD_B(c, 1, 0), b2 = RD_B(c, 0, 1), b3 = RD_B(c, 1, 1);
    __builtin_amdgcn_s_setprio(1);
    acc[0][0] = mfma_16x16x32(a0, b0, acc[0][0]);
    acc[1][0] = mfma_16x16x32(a1, b0, acc[1][0]);
    acc[2][0] = mfma_16x16x32(a2, b0, acc[2][0]);
    acc[3][0] = mfma_16x16x32(a3, b0, acc[3][0]);
    acc[0][1] = mfma_16x16x32(a0, b1, acc[0][1]);
    acc[1][1] = mfma_16x16x32(a1, b1, acc[1][1]);
    acc[2][1] = mfma_16x16x32(a2, b1, acc[2][1]);
    acc[3][1] = mfma_16x16x32(a3, b1, acc[3][1]);
    acc[0][0] = mfma_16x16x32(a4, b2, acc[0][0]);
    acc[1][0] = mfma_16x16x32(a5, b2, acc[1][0]);
    acc[2][0] = mfma_16x16x32(a6, b2, acc[2][0]);
    acc[3][0] = mfma_16x16x32(a7, b2, acc[3][0]);
    acc[0][1] = mfma_16x16x32(a4, b3, acc[0][1]);
    acc[1][1] = mfma_16x16x32(a5, b3, acc[1][1]);
    acc[2][1] = mfma_16x16x32(a6, b3, acc[2][1]);
    acc[3][1] = mfma_16x16x32(a7, b3, acc[3][1]);
    __builtin_amdgcn_s_setprio(0);

    // ---- Q01: B n2-3 (4 reads); A m0-3 still live
    short8 c0 = RD_B(c, 2, 0), c1 = RD_B(c, 3, 0), c2 = RD_B(c, 2, 1), c3 = RD_B(c, 3, 1);
    __builtin_amdgcn_s_setprio(1);
    acc[0][2] = mfma_16x16x32(a0, c0, acc[0][2]);
    acc[1][2] = mfma_16x16x32(a1, c0, acc[1][2]);
    acc[2][2] = mfma_16x16x32(a2, c0, acc[2][2]);
    acc[3][2] = mfma_16x16x32(a3, c0, acc[3][2]);
    acc[0][3] = mfma_16x16x32(a0, c1, acc[0][3]);
    acc[1][3] = mfma_16x16x32(a1, c1, acc[1][3]);
    acc[2][3] = mfma_16x16x32(a2, c1, acc[2][3]);
    acc[3][3] = mfma_16x16x32(a3, c1, acc[3][3]);
    acc[0][2] = mfma_16x16x32(a4, c2, acc[0][2]);
    acc[1][2] = mfma_16x16x32(a5, c2, acc[1][2]);
    acc[2][2] = mfma_16x16x32(a6, c2, acc[2][2]);
    acc[3][2] = mfma_16x16x32(a7, c2, acc[3][2]);
    acc[0][3] = mfma_16x16x32(a4, c3, acc[0][3]);
    acc[1][3] = mfma_16x16x32(a5, c3, acc[1][3]);
    acc[2][3] = mfma_16x16x32(a6, c3, acc[2][3]);
    acc[3][3] = mfma_16x16x32(a7, c3, acc[3][3]);
    __builtin_amdgcn_s_setprio(0);
    __builtin_amdgcn_sched_barrier(0);   // keep A m4-7 reads below (caps reg pressure)

    // ---- Q11: A m4-7 (8 reads, overwrite a-regs); B n2-3 still live
    a0 = RD_A(c, 4, 0); a1 = RD_A(c, 5, 0); a2 = RD_A(c, 6, 0); a3 = RD_A(c, 7, 0);
    a4 = RD_A(c, 4, 1); a5 = RD_A(c, 5, 1); a6 = RD_A(c, 6, 1); a7 = RD_A(c, 7, 1);
    __builtin_amdgcn_s_setprio(1);
    acc[4][2] = mfma_16x16x32(a0, c0, acc[4][2]);
    acc[5][2] = mfma_16x16x32(a1, c0, acc[5][2]);
    acc[6][2] = mfma_16x16x32(a2, c0, acc[6][2]);
    acc[7][2] = mfma_16x16x32(a3, c0, acc[7][2]);
    acc[4][3] = mfma_16x16x32(a0, c1, acc[4][3]);
    acc[5][3] = mfma_16x16x32(a1, c1, acc[5][3]);
    acc[6][3] = mfma_16x16x32(a2, c1, acc[6][3]);
    acc[7][3] = mfma_16x16x32(a3, c1, acc[7][3]);
    acc[4][2] = mfma_16x16x32(a4, c2, acc[4][2]);
    acc[5][2] = mfma_16x16x32(a5, c2, acc[5][2]);
    acc[6][2] = mfma_16x16x32(a6, c2, acc[6][2]);
    acc[7][2] = mfma_16x16x32(a7, c2, acc[7][2]);
    acc[4][3] = mfma_16x16x32(a4, c3, acc[4][3]);
    acc[5][3] = mfma_16x16x32(a5, c3, acc[5][3]);
    acc[6][3] = mfma_16x16x32(a6, c3, acc[6][3]);
    acc[7][3] = mfma_16x16x32(a7, c3, acc[7][3]);
    __builtin_amdgcn_s_setprio(0);

    // ---- Q10: no reads (A m4-7 + B n0-1 live)
    __builtin_amdgcn_s_setprio(1);
    acc[4][0] = mfma_16x16x32(a0, b0, acc[4][0]);
    acc[5][0] = mfma_16x16x32(a1, b0, acc[5][0]);
    acc[6][0] = mfma_16x16x32(a2, b0, acc[6][0]);
    acc[7][0] = mfma_16x16x32(a3, b0, acc[7][0]);
    acc[4][1] = mfma_16x16x32(a0, b1, acc[4][1]);
    acc[5][1] = mfma_16x16x32(a1, b1, acc[5][1]);
    acc[6][1] = mfma_16x16x32(a2, b1, acc[6][1]);
    acc[7][1] = mfma_16x16x32(a3, b1, acc[7][1]);
    acc[4][0] = mfma_16x16x32(a4, b2, acc[4][0]);
    acc[5][0] = mfma_16x16x32(a5, b2, acc[5][0]);
    acc[6][0] = mfma_16x16x32(a6, b2, acc[6][0]);
    acc[7][0] = mfma_16x16x32(a7, b2, acc[7][0]);
    acc[4][1] = mfma_16x16x32(a4, b3, acc[4][1]);
    acc[5][1] = mfma_16x16x32(a5, b3, acc[5][1]);
    acc[6][1] = mfma_16x16x32(a6, b3, acc[6][1]);
    acc[7][1] = mfma_16x16x32(a7, b3, acc[7][1]);
    __builtin_amdgcn_s_setprio(0);

    // tile boundary: next-tile loads are ~a full K-tile old -> drain ~free
    asm volatile("s_waitcnt vmcnt(0)" ::: "memory");
    __builtin_amdgcn_s_barrier();
  }
#undef STAGE_A
#undef STAGE_B
#undef RD_A
#undef RD_B

  // epilogue
  const int row0 = bm + wm * 128 + lg * 4;
  const int col0 = bn + wn * 64 + lr;
  #pragma unroll
  for (int n = 0; n < 4; ++n) {
    const int col = col0 + n * 16;
    const float bv = BIAS ? bias[col] : 0.0f;
    #pragma unroll
    for (int m = 0; m < 8; ++m) {
      #pragma unroll
      for (int r = 0; r < 4; ++r) {
        const long row = row0 + m * 16 + r;
        const float v = acc[m][n][r] + bv;
        if (OUTF32) ((float*)Cout)[row * N + col] = v;
        else        ((bf16*)Cout)[row * N + col] = __float2bfloat16(v);
      }
    }
  }
}

// ---------------- GEMM2: r2's proven m97-structure 128x128 ----------------
template<int BIAS, int OUTF32>
__global__ __launch_bounds__(256, 2)
void gemm_bt(const bf16* __restrict__ A, const bf16* __restrict__ BT,
             const float* __restrict__ bias, void* __restrict__ Cout,
             int M, int N, int K) {
  __shared__ __align__(16) bf16 As[128 * 64];
  __shared__ __align__(16) bf16 Bs[128 * 64];

  const int tid  = threadIdx.x;
  const int lane = tid & 63;
  const int wid  = tid >> 6;
  const int wr   = wid >> 1;
  const int wc   = wid & 1;
  const int lr   = lane & 15;
  const int lg   = lane >> 4;

  const int bm = blockIdx.y * 128;
  const int bn = blockIdx.x * 128;

  const int sboff = wid * 4096;
  const int soff  = sboff + lane * 16;
  const int srow  = soff >> 7;
  const int scol  = (soff & 127) >> 1;

  const bf16* Ag = A  + (long)(bm + srow) * K + scol;
  const bf16* Bg = BT + (long)(bn + srow) * K + scol;
  bf16* Asl = As + (sboff >> 1);
  bf16* Bsl = Bs + (sboff >> 1);

  f32x4 acc[4][4] = {};

  for (int k0 = 0; k0 < K; k0 += 64) {
    #pragma unroll
    for (int j = 0; j < 4; ++j) {
      GLOAD_LDS16(Ag + (long)(j * 8) * K + k0, Asl + j * 512);
      GLOAD_LDS16(Bg + (long)(j * 8) * K + k0, Bsl + j * 512);
    }
    __syncthreads();
    #pragma unroll
    for (int kk = 0; kk < 64; kk += 32) {
      short8 af[4], bfm[4];
      #pragma unroll
      for (int m = 0; m < 4; ++m)
        af[m] = *(const short8*)(As + (wr * 64 + m * 16 + lr) * 64 + kk + lg * 8);
      #pragma unroll
      for (int n = 0; n < 4; ++n)
        bfm[n] = *(const short8*)(Bs + (wc * 64 + n * 16 + lr) * 64 + kk + lg * 8);
      #pragma unroll
      for (int m = 0; m < 4; ++m)
        #pragma unroll
        for (int n = 0; n < 4; ++n)
          acc[m][n] = mfma_16x16x32(af[m], bfm[n], acc[m][n]);
    }
    __syncthreads();
  }

  const int row0 = bm + wr * 64 + lg * 4;
  const int col0 = bn + wc * 64 + lr;
  #pragma unroll
  for (int n = 0; n < 4; ++n) {
    const int col = col0 + n * 16;
    const float bv = BIAS ? bias[col] : 0.0f;
    #pragma unroll
    for (int m = 0; m < 4; ++m) {
      #pragma unroll
      for (int r = 0; r < 4; ++r) {
        const long row = row0 + m * 16 + r;
        const float v = acc[m][n][r] + bv;
        if (OUTF32) ((float*)Cout)[row * N + col] = v;
        else        ((bf16*)Cout)[row * N + col] = __float2bfloat16(v);
      }
    }
  }
}

// ---------------- RMSNorm over q,k head rows (128 elems), one wave per row ----------------
__global__ __launch_bounds__(256)
void rmsnorm_qk(bf16* __restrict__ qkv, const float* __restrict__ qw,
                const float* __restrict__ kw) {
  const int row  = blockIdx.x * 4 + (threadIdx.x >> 6);
  const int lane = threadIdx.x & 63;
  const int token = row / 48;
  const int rem   = row - token * 48;
  const int which = rem / 24;
  const int head  = rem - which * 24;
  bf16* p = qkv + (long)token * QKVN + which * HID + head * HD;
  const float a = __bfloat162float(p[lane * 2]);
  const float b = __bfloat162float(p[lane * 2 + 1]);
  float ss = a * a + b * b;
  #pragma unroll
  for (int mask = 32; mask >= 1; mask >>= 1) ss += __shfl_xor(ss, mask);
  const float inv = rsqrtf(ss * (1.0f / 128.0f) + 1e-6f);
  const float* w = which ? kw : qw;
  p[lane * 2]     = __float2bfloat16(a * inv * w[lane * 2]);
  p[lane * 2 + 1] = __float2bfloat16(b * inv * w[lane * 2 + 1]);
}

// ---------------- flash attention (r3 version): block = (64 q rows, 1 head) ----------------
__global__ __launch_bounds__(256, 2)
void attn_kernel(const bf16* __restrict__ qkv, bf16* __restrict__ ctx) {
  const int head = blockIdx.y;
  const int qb   = blockIdx.x;
  const int tid  = threadIdx.x;
  const int lane = tid & 63;
  const int wid  = tid >> 6;
  const int lr   = lane & 15;
  const int lg   = lane >> 4;

  __shared__ __align__(16) unsigned char Ksb[64 * 256];
  __shared__ __align__(16) unsigned char Vsb[128 * 128];
  __shared__ __align__(16) unsigned short Ps[4][16 * 72];

  const int qrow0 = qb * 64 + wid * 16;
  short8 qf[4];
  #pragma unroll
  for (int kt = 0; kt < 4; ++kt)
    qf[kt] = *(const short8*)(qkv + (long)(qrow0 + lr) * QKVN + head * HD + kt * 32 + lg * 8);

  f32x4 oacc[8] = {};
  float mrun[4], lrun[4];
  #pragma unroll
  for (int r = 0; r < 4; ++r) { mrun[r] = -1e30f; lrun[r] = 0.0f; }

  const float scale = 0.088388347648318447f;   // 1/sqrt(128)

  for (int t = 0; t < SEQ / 64; ++t) {
    const int kv0 = t * 64;
    short8 kreg[4], vreg[4];
    int tokv[4], dchv[4];
    #pragma unroll
    for (int j = 0; j < 4; ++j) {
      const int id  = tid + j * 256;
      const int tok = id >> 4;
      const int dc  = id & 15;
      tokv[j] = tok; dchv[j] = dc;
      kreg[j] = *(const short8*)(qkv + (long)(kv0 + tok) * QKVN + HID     + head * HD + dc * 8);
      vreg[j] = *(const short8*)(qkv + (long)(kv0 + tok) * QKVN + 2 * HID + head * HD + dc * 8);
    }
    __syncthreads();
    #pragma unroll
    for (int j = 0; j < 4; ++j) {
      const int tok = tokv[j], dc = dchv[j];
      *(short8*)(Ksb + ((tok * 256 + dc * 16) ^ ((tok & 7) << 4))) = kreg[j];
      const int dg = dc >> 1, h = dc & 1, kg = tok >> 2, kr = tok & 3;
      const int pos = (kg & 8) | ((kg & 1) << 2) | ((kg >> 1) & 3);
      *(short8*)(Vsb + (dg * 16 + pos) * 128 + kr * 32 + h * 16) = vreg[j];
    }
    __syncthreads();

    f32x4 s[4];
    __builtin_amdgcn_s_setprio(1);
    #pragma unroll
    for (int ct = 0; ct < 4; ++ct) {
      f32x4 a = {};
      #pragma unroll
      for (int kt = 0; kt < 4; ++kt) {
        short8 kb = *(const short8*)(Ksb +
            ((((ct * 16 + lr) * 256) + kt * 64 + lg * 16) ^ ((lr & 7) << 4)));
        a = mfma_16x16x32(qf[kt], kb, a);
      }
      s[ct] = a;
    }
    __builtin_amdgcn_s_setprio(0);

    #pragma unroll
    for (int r = 0; r < 4; ++r) {
      float pm = fmaxf(fmaxf(s[0][r], s[1][r]), fmaxf(s[2][r], s[3][r]));
      #pragma unroll
      for (int mask = 1; mask <= 8; mask <<= 1) pm = fmaxf(pm, __shfl_xor(pm, mask));
      pm *= scale;
      const float mnew = fmaxf(mrun[r], pm);
      const float corr = __expf(mrun[r] - mnew);
      float psum = 0.0f;
      #pragma unroll
      for (int ct = 0; ct < 4; ++ct) {
        const float p = __expf(s[ct][r] * scale - mnew);
        psum += p;
        bf16 pb = __float2bfloat16(p);
        Ps[wid][(lg * 4 + r) * 72 + ct * 16 + lr] = *(unsigned short*)&pb;
      }
      #pragma unroll
      for (int mask = 1; mask <= 8; mask <<= 1) psum += __shfl_xor(psum, mask);
      lrun[r] = lrun[r] * corr + psum;
      mrun[r] = mnew;
      #pragma unroll
      for (int dt = 0; dt < 8; ++dt) oacc[dt][r] *= corr;
    }

    short8 pa[2];
    #pragma unroll
    for (int kt = 0; kt < 2; ++kt)
      pa[kt] = *(const short8*)&Ps[wid][lr * 72 + kt * 32 + lg * 8];

    lds_cchar* vb0 = (lds_cchar*)Vsb + lane * 8;
    __builtin_amdgcn_s_setprio(1);
    #pragma unroll
    for (int dt = 0; dt < 8; ++dt) {
      lds_cchar* pd = vb0 + dt * 2048;
      ull r0, r1, r2, r3;
      asm volatile("ds_read_b64_tr_b16 %0, %1 offset:0"    : "=v"(r0) : "v"(pd));
      asm volatile("ds_read_b64_tr_b16 %0, %1 offset:512"  : "=v"(r1) : "v"(pd));
      asm volatile("ds_read_b64_tr_b16 %0, %1 offset:1024" : "=v"(r2) : "v"(pd));
      asm volatile("ds_read_b64_tr_b16 %0, %1 offset:1536" : "=v"(r3) : "v"(pd));
      asm volatile("s_waitcnt lgkmcnt(0)" ::: "memory");
      __builtin_amdgcn_sched_barrier(0);
      short8 vb_0, vb_1;
      ((ull*)&vb_0)[0] = r0; ((ull*)&vb_0)[1] = r1;
      ((ull*)&vb_1)[0] = r2; ((ull*)&vb_1)[1] = r3;
      oacc[dt] = mfma_16x16x32(pa[0], vb_0, oacc[dt]);
      oacc[dt] = mfma_16x16x32(pa[1], vb_1, oacc[dt]);
    }
    __builtin_amdgcn_s_setprio(0);
  }

  #pragma unroll
  for (int r = 0; r < 4; ++r) {
    const float inv = 1.0f / lrun[r];
    const long tok = qrow0 + lg * 4 + r;
    #pragma unroll
    for (int dt = 0; dt < 8; ++dt)
      ctx[tok * HID + head * HD + dt * 16 + lr] = __float2bfloat16(oacc[dt][r] * inv);
  }
}

extern "C" void kernel_launch(void* const* d_in, const int* in_sizes, int n_in,
                              void* d_out, int out_size, void* d_ws, size_t ws_size,
                              hipStream_t stream) {
  (void)in_sizes; (void)n_in; (void)out_size; (void)ws_size;
  const float* x     = (const float*)d_in[0];
  const float* Wqkv  = (const float*)d_in[1];
  const float* bqkv  = (const float*)d_in[2];
  const float* Wproj = (const float*)d_in[3];
  const float* qw    = (const float*)d_in[4];
  const float* kw    = (const float*)d_in[5];

  char* ws = (char*)d_ws;
  bf16* xb     = (bf16*)ws;                     // 2048x3072 bf16
  bf16* WqkvT  = (bf16*)(ws + 12582912);        // 9216x3072 bf16
  bf16* WprojT = (bf16*)(ws + 69206016);        // 3072x3072 bf16
  bf16* qkv    = (bf16*)(ws + 88080384);        // 2048x9216 bf16
  bf16* ctx    = xb;                            // xb dead after GEMM1

  cvt_f32_bf16_vec<<<(SEQ * HID / 4 + 255) / 256, 256, 0, stream>>>(x, xb, SEQ * HID / 4);
  transpose_cvt<<<dim3(QKVN / 32, HID / 32), 256, 0, stream>>>(Wqkv, WqkvT, HID, QKVN);
  transpose_cvt<<<dim3(HID / 32, HID / 32), 256, 0, stream>>>(Wproj, WprojT, HID, HID);

  // GEMM1: 8 M-tiles x 36 N-tiles of 256 -> 288 blocks, bm fastest
  gemm256v2<1, 0><<<288, 512, 0, stream>>>(xb, WqkvT, bqkv, (void*)qkv,
                                           SEQ, QKVN, HID, 8);

  rmsnorm_qk<<<SEQ * 48 / 4, 256, 0, stream>>>(qkv, qw, kw);

  attn_kernel<<<dim3(SEQ / 64, NH), 256, 0, stream>>>(qkv, ctx);

  // GEMM2: 384 blocks of 128x128 (2+/CU, good fill for the small GEMM)
  gemm_bt<0, 1><<<dim3(HID / 128, SEQ / 128), 256, 0, stream>>>(
      ctx, WprojT, nullptr, d_out, SEQ, HID, HID);
}

// Round 7
// 379.184 us; speedup vs baseline: 1.2226x; 1.2226x over previous
//
#include <hip/hip_runtime.h>
#include <hip/hip_bf16.h>

using bf16 = __hip_bfloat16;
typedef __attribute__((ext_vector_type(8))) short short8;   // 8 x bf16 fragment (4 VGPRs)
typedef __attribute__((ext_vector_type(4))) float f32x4;
typedef unsigned long long ull;

static constexpr int SEQ  = 2048;
static constexpr int HID  = 3072;
static constexpr int NH   = 24;
static constexpr int HD   = 128;
static constexpr int QKVN = 9216;

__device__ __forceinline__ f32x4 mfma_16x16x32(short8 a, short8 b, f32x4 c) {
  return __builtin_amdgcn_mfma_f32_16x16x32_bf16(a, b, c, 0, 0, 0);
}

#define GLOAD_LDS16(g, l) __builtin_amdgcn_global_load_lds(                 \
    (const __attribute__((address_space(1))) void*)(g),                    \
    (__attribute__((address_space(3))) void*)(l), 16, 0, 0)

typedef __attribute__((address_space(3))) const unsigned char lds_cchar;

// ---------------- fp32 -> bf16 vectorized convert ----------------
__global__ __launch_bounds__(256)
void cvt_f32_bf16_vec(const float* __restrict__ src, bf16* __restrict__ dst, int n4) {
  int i = blockIdx.x * 256 + threadIdx.x;
  if (i >= n4) return;
  float4 v = ((const float4*)src)[i];
  ushort4 o;
  bf16 t0 = __float2bfloat16(v.x); o.x = *(unsigned short*)&t0;
  bf16 t1 = __float2bfloat16(v.y); o.y = *(unsigned short*)&t1;
  bf16 t2 = __float2bfloat16(v.z); o.z = *(unsigned short*)&t2;
  bf16 t3 = __float2bfloat16(v.w); o.w = *(unsigned short*)&t3;
  ((ushort4*)dst)[i] = o;
}

// ---------------- fp32 (R x C) -> bf16 transposed (C x R), vectorized stores ----------------
// tile: 32 src-rows x 64 src-cols; stores ushort2 (r-pairs), padded LDS (2-way max conflict)
__global__ __launch_bounds__(256)
void transpose_cvt64(const float* __restrict__ src, bf16* __restrict__ dst, int R, int C) {
  __shared__ float tile[32][65];
  const int c0 = blockIdx.x * 64, r0 = blockIdx.y * 32;
  const int lc = threadIdx.x & 63, lt = threadIdx.x >> 6;
  #pragma unroll
  for (int i = 0; i < 8; ++i)
    tile[lt + i * 4][lc] = src[(size_t)(r0 + lt + i * 4) * C + c0 + lc];
  __syncthreads();
  const int u = threadIdx.x & 15, dr = threadIdx.x >> 4;   // u: r-pair 0..15, dr: 0..15
  #pragma unroll
  for (int j = 0; j < 4; ++j) {
    const int cc = dr + j * 16;                            // dst row (source col)
    bf16 x0 = __float2bfloat16(tile[u * 2][cc]);
    bf16 x1 = __float2bfloat16(tile[u * 2 + 1][cc]);
    ushort2 o;
    o.x = *(unsigned short*)&x0; o.y = *(unsigned short*)&x1;
    *(ushort2*)&dst[(size_t)(c0 + cc) * R + r0 + u * 2] = o;
  }
}

// ---------------- GEMM1: 256x288 tile, grid EXACTLY 256 blocks, 12 waves ----------------
// waves 2M x 6N (per-wave 128x48); dbuf-2 LDS 136 KB; 4 phases/K-tile (kk x m-half),
// 12 MFMA each, keeps live regs ~150 (3 waves/SIMD needs <=168 VGPR).
// Staging: 68 wave-loads (A 32, B 36), L = wid + 12*i, spread P1/P2 of prior tile;
// single vmcnt(0)+barrier at tile start (loads >=2 phases old; per-wave counts
// published by the barrier). T2 swizzle: source chunk (lane&7)^(lane>>3), linear
// LDS dest, read chunk (kk*4+lg)^(lr&7).
template<int BIAS>
__global__ __launch_bounds__(768, 3)
void gemm12w(const bf16* __restrict__ A, const bf16* __restrict__ BT,
             const float* __restrict__ bias, bf16* __restrict__ Cout,
             int M, int N, int K) {
  __shared__ __align__(16) bf16 Asb[2][256 * 64];
  __shared__ __align__(16) bf16 Bsb[2][288 * 64];

  const int tid  = threadIdx.x;
  const int lane = tid & 63;
  const int wid  = tid >> 6;          // 0..11
  const int wm   = wid / 6;           // 0..1 -> rows wm*128..
  const int wn   = wid % 6;           // 0..5 -> cols wn*48..
  const int lr   = lane & 15;
  const int lg   = lane >> 4;

  const int bm = (blockIdx.x & 7) * 256;   // XCD x owns one M-strip (A L2-resident)
  const int bn = (blockIdx.x >> 3) * 288;

  const int lrow = lane >> 3;
  const int csrc = ((lane & 7) ^ lrow) * 8;
  const bf16* Abase = A  + (size_t)(bm + lrow) * K + csrc;
  const bf16* Bbase = BT + (size_t)(bn + lrow) * K + csrc;

#define STG12(b, u, i) do {                                                       \
    const int L_ = wid + 12 * (i);                                                \
    if (L_ < 32)      GLOAD_LDS16(Abase + (size_t)(8 * L_) * K + (size_t)(u) * 64,\
                                  &Asb[b][L_ * 512]);                             \
    else if (L_ < 68) GLOAD_LDS16(Bbase + (size_t)(8 * (L_ - 32)) * K + (size_t)(u) * 64, \
                                  &Bsb[b][(L_ - 32) * 512]);                      \
  } while (0)
#define RA12(b, m, kk) (*(const short8*)(&Asb[b][(wm * 128 + (m) * 16 + lr) * 64 \
                          + ((((kk) * 4 + lg)) ^ (lr & 7)) * 8]))
#define RB12(b, n, kk) (*(const short8*)(&Bsb[b][(wn * 48 + (n) * 16 + lr) * 64 \
                          + ((((kk) * 4 + lg)) ^ (lr & 7)) * 8]))

  f32x4 acc[8][3] = {};
  const int NT = K >> 6;   // 48

  #pragma unroll
  for (int i = 0; i < 6; ++i) STG12(0, 0, i);

  for (int t = 0; t < NT; ++t) {
    const int c = t & 1, nc = c ^ 1;
    const bool pf = (t + 1) < NT;
    short8 a[4], b[3];

    // tile boundary: certify this tile's staged data (issued >=2 phases ago)
    asm volatile("s_waitcnt vmcnt(0)" ::: "memory");
    __builtin_amdgcn_s_barrier();

    // ---- P1: kk0 x m0-3 ; stage 3 of tile t+1
    if (pf) { STG12(nc, t + 1, 0); STG12(nc, t + 1, 1); STG12(nc, t + 1, 2); }
    __builtin_amdgcn_sched_barrier(0);
    b[0] = RB12(c, 0, 0); b[1] = RB12(c, 1, 0); b[2] = RB12(c, 2, 0);
    a[0] = RA12(c, 0, 0); a[1] = RA12(c, 1, 0); a[2] = RA12(c, 2, 0); a[3] = RA12(c, 3, 0);
    __builtin_amdgcn_s_setprio(1);
    #pragma unroll
    for (int n = 0; n < 3; ++n)
      #pragma unroll
      for (int m = 0; m < 4; ++m) acc[m][n] = mfma_16x16x32(a[m], b[n], acc[m][n]);
    __builtin_amdgcn_s_setprio(0);
    __builtin_amdgcn_s_barrier();

    // ---- P2: kk0 x m4-7 ; stage remaining 3
    if (pf) { STG12(nc, t + 1, 3); STG12(nc, t + 1, 4); STG12(nc, t + 1, 5); }
    __builtin_amdgcn_sched_barrier(0);
    a[0] = RA12(c, 4, 0); a[1] = RA12(c, 5, 0); a[2] = RA12(c, 6, 0); a[3] = RA12(c, 7, 0);
    __builtin_amdgcn_s_setprio(1);
    #pragma unroll
    for (int n = 0; n < 3; ++n)
      #pragma unroll
      for (int m = 0; m < 4; ++m) acc[4 + m][n] = mfma_16x16x32(a[m], b[n], acc[4 + m][n]);
    __builtin_amdgcn_s_setprio(0);
    __builtin_amdgcn_s_barrier();

    // ---- P3: kk1 x m0-3
    b[0] = RB12(c, 0, 1); b[1] = RB12(c, 1, 1); b[2] = RB12(c, 2, 1);
    a[0] = RA12(c, 0, 1); a[1] = RA12(c, 1, 1); a[2] = RA12(c, 2, 1); a[3] = RA12(c, 3, 1);
    __builtin_amdgcn_s_setprio(1);
    #pragma unroll
    for (int n = 0; n < 3; ++n)
      #pragma unroll
      for (int m = 0; m < 4; ++m) acc[m][n] = mfma_16x16x32(a[m], b[n], acc[m][n]);
    __builtin_amdgcn_s_setprio(0);
    __builtin_amdgcn_s_barrier();

    // ---- P4: kk1 x m4-7  (loop-top vmcnt+barrier separates next tile's staging)
    a[0] = RA12(c, 4, 1); a[1] = RA12(c, 5, 1); a[2] = RA12(c, 6, 1); a[3] = RA12(c, 7, 1);
    __builtin_amdgcn_s_setprio(1);
    #pragma unroll
    for (int n = 0; n < 3; ++n)
      #pragma unroll
      for (int m = 0; m < 4; ++m) acc[4 + m][n] = mfma_16x16x32(a[m], b[n], acc[4 + m][n]);
    __builtin_amdgcn_s_setprio(0);
  }
#undef STG12
#undef RA12
#undef RB12

  const int row0 = bm + wm * 128 + lg * 4;
  const int col0 = bn + wn * 48 + lr;
  #pragma unroll
  for (int n = 0; n < 3; ++n) {
    const int col = col0 + n * 16;
    const float bv = BIAS ? bias[col] : 0.0f;
    #pragma unroll
    for (int m = 0; m < 8; ++m)
      #pragma unroll
      for (int r = 0; r < 4; ++r)
        Cout[(size_t)(row0 + m * 16 + r) * N + col] = __float2bfloat16(acc[m][n][r] + bv);
  }
}

// ---------------- GEMM2: 128x192 tile, grid EXACTLY 256 (16x16), 8 waves ----------------
__global__ __launch_bounds__(512, 2)
void gemm8w(const bf16* __restrict__ A, const bf16* __restrict__ BT,
            float* __restrict__ Cout, int M, int N, int K) {
  __shared__ __align__(16) bf16 Asb[2][128 * 64];
  __shared__ __align__(16) bf16 Bsb[2][192 * 64];

  const int tid  = threadIdx.x;
  const int lane = tid & 63;
  const int wid  = tid >> 6;          // 0..7
  const int wm   = wid >> 2;          // 0..1 -> rows wm*64..
  const int wn   = wid & 3;           // 0..3 -> cols wn*48..
  const int lr   = lane & 15;
  const int lg   = lane >> 4;

  // XCD x gets M-strips {2x, 2x+1} (A rows L2-resident per XCD)
  const int bm = (2 * (blockIdx.x & 7) + ((blockIdx.x >> 3) & 1)) * 128;
  const int bn = (blockIdx.x >> 4) * 192;

  const int lrow = lane >> 3;
  const int csrc = ((lane & 7) ^ lrow) * 8;
  const bf16* Abase = A  + (size_t)(bm + lrow) * K + csrc;
  const bf16* Bbase = BT + (size_t)(bn + lrow) * K + csrc;

#define STG8(b, u, i) do {                                                        \
    const int L_ = wid + 8 * (i);                                                 \
    if (L_ < 16)      GLOAD_LDS16(Abase + (size_t)(8 * L_) * K + (size_t)(u) * 64,\
                                  &Asb[b][L_ * 512]);                             \
    else              GLOAD_LDS16(Bbase + (size_t)(8 * (L_ - 16)) * K + (size_t)(u) * 64, \
                                  &Bsb[b][(L_ - 16) * 512]);                      \
  } while (0)
#define RA8(b, m, kk) (*(const short8*)(&Asb[b][(wm * 64 + (m) * 16 + lr) * 64 \
                          + ((((kk) * 4 + lg)) ^ (lr & 7)) * 8]))
#define RB8(b, n, kk) (*(const short8*)(&Bsb[b][(wn * 48 + (n) * 16 + lr) * 64 \
                          + ((((kk) * 4 + lg)) ^ (lr & 7)) * 8]))

  f32x4 acc[4][3] = {};
  const int NT = K >> 6;   // 48

  #pragma unroll
  for (int i = 0; i < 5; ++i) STG8(0, 0, i);

  for (int t = 0; t < NT; ++t) {
    const int c = t & 1, nc = c ^ 1;
    const bool pf = (t + 1) < NT;
    short8 a[4], b[3];

    asm volatile("s_waitcnt vmcnt(0)" ::: "memory");
    __builtin_amdgcn_s_barrier();

    // ---- P1: kk0 ; stage 3
    if (pf) { STG8(nc, t + 1, 0); STG8(nc, t + 1, 1); STG8(nc, t + 1, 2); }
    __builtin_amdgcn_sched_barrier(0);
    b[0] = RB8(c, 0, 0); b[1] = RB8(c, 1, 0); b[2] = RB8(c, 2, 0);
    a[0] = RA8(c, 0, 0); a[1] = RA8(c, 1, 0); a[2] = RA8(c, 2, 0); a[3] = RA8(c, 3, 0);
    __builtin_amdgcn_s_setprio(1);
    #pragma unroll
    for (int n = 0; n < 3; ++n)
      #pragma unroll
      for (int m = 0; m < 4; ++m) acc[m][n] = mfma_16x16x32(a[m], b[n], acc[m][n]);
    __builtin_amdgcn_s_setprio(0);
    __builtin_amdgcn_s_barrier();

    // ---- P2: kk1 ; stage 2
    if (pf) { STG8(nc, t + 1, 3); STG8(nc, t + 1, 4); }
    __builtin_amdgcn_sched_barrier(0);
    b[0] = RB8(c, 0, 1); b[1] = RB8(c, 1, 1); b[2] = RB8(c, 2, 1);
    a[0] = RA8(c, 0, 1); a[1] = RA8(c, 1, 1); a[2] = RA8(c, 2, 1); a[3] = RA8(c, 3, 1);
    __builtin_amdgcn_s_setprio(1);
    #pragma unroll
    for (int n = 0; n < 3; ++n)
      #pragma unroll
      for (int m = 0; m < 4; ++m) acc[m][n] = mfma_16x16x32(a[m], b[n], acc[m][n]);
    __builtin_amdgcn_s_setprio(0);
  }
#undef STG8
#undef RA8
#undef RB8

  const int row0 = bm + wm * 64 + lg * 4;
  const int col0 = bn + wn * 48 + lr;
  #pragma unroll
  for (int n = 0; n < 3; ++n) {
    const int col = col0 + n * 16;
    #pragma unroll
    for (int m = 0; m < 4; ++m)
      #pragma unroll
      for (int r = 0; r < 4; ++r)
        Cout[(size_t)(row0 + m * 16 + r) * N + col] = acc[m][n][r];
  }
}

// ---------------- RMSNorm over q,k head rows (128 elems), one wave per row ----------------
__global__ __launch_bounds__(256)
void rmsnorm_qk(bf16* __restrict__ qkv, const float* __restrict__ qw,
                const float* __restrict__ kw) {
  const int row  = blockIdx.x * 4 + (threadIdx.x >> 6);
  const int lane = threadIdx.x & 63;
  const int token = row / 48;
  const int rem   = row - token * 48;
  const int which = rem / 24;
  const int head  = rem - which * 24;
  bf16* p = qkv + (long)token * QKVN + which * HID + head * HD;
  const float a = __bfloat162float(p[lane * 2]);
  const float b = __bfloat162float(p[lane * 2 + 1]);
  float ss = a * a + b * b;
  #pragma unroll
  for (int mask = 32; mask >= 1; mask >>= 1) ss += __shfl_xor(ss, mask);
  const float inv = rsqrtf(ss * (1.0f / 128.0f) + 1e-6f);
  const float* w = which ? kw : qw;
  p[lane * 2]     = __float2bfloat16(a * inv * w[lane * 2]);
  p[lane * 2 + 1] = __float2bfloat16(b * inv * w[lane * 2 + 1]);
}

// ---------------- flash attention (r3-proven): block = (64 q rows, 1 head) ----------------
__global__ __launch_bounds__(256, 2)
void attn_kernel(const bf16* __restrict__ qkv, bf16* __restrict__ ctx) {
  const int head = blockIdx.y;
  const int qb   = blockIdx.x;
  const int tid  = threadIdx.x;
  const int lane = tid & 63;
  const int wid  = tid >> 6;
  const int lr   = lane & 15;
  const int lg   = lane >> 4;

  __shared__ __align__(16) unsigned char Ksb[64 * 256];
  __shared__ __align__(16) unsigned char Vsb[128 * 128];
  __shared__ __align__(16) unsigned short Ps[4][16 * 72];

  const int qrow0 = qb * 64 + wid * 16;
  short8 qf[4];
  #pragma unroll
  for (int kt = 0; kt < 4; ++kt)
    qf[kt] = *(const short8*)(qkv + (long)(qrow0 + lr) * QKVN + head * HD + kt * 32 + lg * 8);

  f32x4 oacc[8] = {};
  float mrun[4], lrun[4];
  #pragma unroll
  for (int r = 0; r < 4; ++r) { mrun[r] = -1e30f; lrun[r] = 0.0f; }

  const float scale = 0.088388347648318447f;   // 1/sqrt(128)

  for (int t = 0; t < SEQ / 64; ++t) {
    const int kv0 = t * 64;
    short8 kreg[4], vreg[4];
    int tokv[4], dchv[4];
    #pragma unroll
    for (int j = 0; j < 4; ++j) {
      const int id  = tid + j * 256;
      const int tok = id >> 4;
      const int dc  = id & 15;
      tokv[j] = tok; dchv[j] = dc;
      kreg[j] = *(const short8*)(qkv + (long)(kv0 + tok) * QKVN + HID     + head * HD + dc * 8);
      vreg[j] = *(const short8*)(qkv + (long)(kv0 + tok) * QKVN + 2 * HID + head * HD + dc * 8);
    }
    __syncthreads();
    #pragma unroll
    for (int j = 0; j < 4; ++j) {
      const int tok = tokv[j], dc = dchv[j];
      *(short8*)(Ksb + ((tok * 256 + dc * 16) ^ ((tok & 7) << 4))) = kreg[j];
      const int dg = dc >> 1, h = dc & 1, kg = tok >> 2, kr = tok & 3;
      const int pos = (kg & 8) | ((kg & 1) << 2) | ((kg >> 1) & 3);
      *(short8*)(Vsb + (dg * 16 + pos) * 128 + kr * 32 + h * 16) = vreg[j];
    }
    __syncthreads();

    f32x4 s[4];
    __builtin_amdgcn_s_setprio(1);
    #pragma unroll
    for (int ct = 0; ct < 4; ++ct) {
      f32x4 a = {};
      #pragma unroll
      for (int kt = 0; kt < 4; ++kt) {
        short8 kb = *(const short8*)(Ksb +
            ((((ct * 16 + lr) * 256) + kt * 64 + lg * 16) ^ ((lr & 7) << 4)));
        a = mfma_16x16x32(qf[kt], kb, a);
      }
      s[ct] = a;
    }
    __builtin_amdgcn_s_setprio(0);

    #pragma unroll
    for (int r = 0; r < 4; ++r) {
      float pm = fmaxf(fmaxf(s[0][r], s[1][r]), fmaxf(s[2][r], s[3][r]));
      #pragma unroll
      for (int mask = 1; mask <= 8; mask <<= 1) pm = fmaxf(pm, __shfl_xor(pm, mask));
      pm *= scale;
      const float mnew = fmaxf(mrun[r], pm);
      const float corr = __expf(mrun[r] - mnew);
      float psum = 0.0f;
      #pragma unroll
      for (int ct = 0; ct < 4; ++ct) {
        const float p = __expf(s[ct][r] * scale - mnew);
        psum += p;
        bf16 pb = __float2bfloat16(p);
        Ps[wid][(lg * 4 + r) * 72 + ct * 16 + lr] = *(unsigned short*)&pb;
      }
      #pragma unroll
      for (int mask = 1; mask <= 8; mask <<= 1) psum += __shfl_xor(psum, mask);
      lrun[r] = lrun[r] * corr + psum;
      mrun[r] = mnew;
      #pragma unroll
      for (int dt = 0; dt < 8; ++dt) oacc[dt][r] *= corr;
    }

    short8 pa[2];
    #pragma unroll
    for (int kt = 0; kt < 2; ++kt)
      pa[kt] = *(const short8*)&Ps[wid][lr * 72 + kt * 32 + lg * 8];

    lds_cchar* vb0 = (lds_cchar*)Vsb + lane * 8;
    __builtin_amdgcn_s_setprio(1);
    #pragma unroll
    for (int dt = 0; dt < 8; ++dt) {
      lds_cchar* pd = vb0 + dt * 2048;
      ull r0, r1, r2, r3;
      asm volatile("ds_read_b64_tr_b16 %0, %1 offset:0"    : "=v"(r0) : "v"(pd));
      asm volatile("ds_read_b64_tr_b16 %0, %1 offset:512"  : "=v"(r1) : "v"(pd));
      asm volatile("ds_read_b64_tr_b16 %0, %1 offset:1024" : "=v"(r2) : "v"(pd));
      asm volatile("ds_read_b64_tr_b16 %0, %1 offset:1536" : "=v"(r3) : "v"(pd));
      asm volatile("s_waitcnt lgkmcnt(0)" ::: "memory");
      __builtin_amdgcn_sched_barrier(0);
      short8 vb_0, vb_1;
      ((ull*)&vb_0)[0] = r0; ((ull*)&vb_0)[1] = r1;
      ((ull*)&vb_1)[0] = r2; ((ull*)&vb_1)[1] = r3;
      oacc[dt] = mfma_16x16x32(pa[0], vb_0, oacc[dt]);
      oacc[dt] = mfma_16x16x32(pa[1], vb_1, oacc[dt]);
    }
    __builtin_amdgcn_s_setprio(0);
  }

  #pragma unroll
  for (int r = 0; r < 4; ++r) {
    const float inv = 1.0f / lrun[r];
    const long tok = qrow0 + lg * 4 + r;
    #pragma unroll
    for (int dt = 0; dt < 8; ++dt)
      ctx[tok * HID + head * HD + dt * 16 + lr] = __float2bfloat16(oacc[dt][r] * inv);
  }
}

extern "C" void kernel_launch(void* const* d_in, const int* in_sizes, int n_in,
                              void* d_out, int out_size, void* d_ws, size_t ws_size,
                              hipStream_t stream) {
  (void)in_sizes; (void)n_in; (void)out_size; (void)ws_size;
  const float* x     = (const float*)d_in[0];
  const float* Wqkv  = (const float*)d_in[1];
  const float* bqkv  = (const float*)d_in[2];
  const float* Wproj = (const float*)d_in[3];
  const float* qw    = (const float*)d_in[4];
  const float* kw    = (const float*)d_in[5];

  char* ws = (char*)d_ws;
  bf16* xb     = (bf16*)ws;                     // 2048x3072 bf16
  bf16* WqkvT  = (bf16*)(ws + 12582912);        // 9216x3072 bf16
  bf16* WprojT = (bf16*)(ws + 69206016);        // 3072x3072 bf16
  bf16* qkv    = (bf16*)(ws + 88080384);        // 2048x9216 bf16
  bf16* ctx    = xb;                            // xb dead after GEMM1

  cvt_f32_bf16_vec<<<(SEQ * HID / 4 + 255) / 256, 256, 0, stream>>>(x, xb, SEQ * HID / 4);
  transpose_cvt64<<<dim3(QKVN / 64, HID / 32), 256, 0, stream>>>(Wqkv, WqkvT, HID, QKVN);
  transpose_cvt64<<<dim3(HID / 64, HID / 32), 256, 0, stream>>>(Wproj, WprojT, HID, HID);

  // GEMM1: 8 M x 32 N tiles of 256x288 -> exactly 256 blocks (one round, no tail)
  gemm12w<1><<<256, 768, 0, stream>>>(xb, WqkvT, bqkv, qkv, SEQ, QKVN, HID);

  rmsnorm_qk<<<SEQ * 48 / 4, 256, 0, stream>>>(qkv, qw, kw);

  attn_kernel<<<dim3(SEQ / 64, NH), 256, 0, stream>>>(qkv, ctx);

  // GEMM2: 16 M x 16 N tiles of 128x192 -> exactly 256 blocks
  gemm8w<<<256, 512, 0, stream>>>(ctx, WprojT, (float*)d_out, SEQ, HID, HID);
}

// Round 8
// 355.617 us; speedup vs baseline: 1.3037x; 1.0663x over previous
//
#include <hip/hip_runtime.h>
#include <hip/hip_bf16.h>

using bf16 = __hip_bfloat16;
typedef __attribute__((ext_vector_type(8))) short short8;   // 8 x bf16 fragment (4 VGPRs)
typedef __attribute__((ext_vector_type(4))) float f32x4;
typedef unsigned long long ull;

static constexpr int SEQ  = 2048;
static constexpr int HID  = 3072;
static constexpr int NH   = 24;
static constexpr int HD   = 128;
static constexpr int QKVN = 9216;

__device__ __forceinline__ f32x4 mfma_16x16x32(short8 a, short8 b, f32x4 c) {
  return __builtin_amdgcn_mfma_f32_16x16x32_bf16(a, b, c, 0, 0, 0);
}

#define GLOAD_LDS16(g, l) __builtin_amdgcn_global_load_lds(                 \
    (const __attribute__((address_space(1))) void*)(g),                    \
    (__attribute__((address_space(3))) void*)(l), 16, 0, 0)

typedef __attribute__((address_space(3))) const unsigned char lds_cchar;

// ---------------- fp32 -> bf16 vectorized convert ----------------
__global__ __launch_bounds__(256)
void cvt_f32_bf16_vec(const float* __restrict__ src, bf16* __restrict__ dst, int n4) {
  int i = blockIdx.x * 256 + threadIdx.x;
  if (i >= n4) return;
  float4 v = ((const float4*)src)[i];
  ushort4 o;
  bf16 t0 = __float2bfloat16(v.x); o.x = *(unsigned short*)&t0;
  bf16 t1 = __float2bfloat16(v.y); o.y = *(unsigned short*)&t1;
  bf16 t2 = __float2bfloat16(v.z); o.z = *(unsigned short*)&t2;
  bf16 t3 = __float2bfloat16(v.w); o.w = *(unsigned short*)&t3;
  ((ushort4*)dst)[i] = o;
}

// ---------------- fp32 (R x C) -> bf16 transposed (C x R), vectorized stores ----------------
__global__ __launch_bounds__(256)
void transpose_cvt64(const float* __restrict__ src, bf16* __restrict__ dst, int R, int C) {
  __shared__ float tile[32][65];
  const int c0 = blockIdx.x * 64, r0 = blockIdx.y * 32;
  const int lc = threadIdx.x & 63, lt = threadIdx.x >> 6;
  #pragma unroll
  for (int i = 0; i < 8; ++i)
    tile[lt + i * 4][lc] = src[(size_t)(r0 + lt + i * 4) * C + c0 + lc];
  __syncthreads();
  const int u = threadIdx.x & 15, dr = threadIdx.x >> 4;
  #pragma unroll
  for (int j = 0; j < 4; ++j) {
    const int cc = dr + j * 16;
    bf16 x0 = __float2bfloat16(tile[u * 2][cc]);
    bf16 x1 = __float2bfloat16(tile[u * 2 + 1][cc]);
    ushort2 o;
    o.x = *(unsigned short*)&x0; o.y = *(unsigned short*)&x1;
    *(ushort2*)&dst[(size_t)(c0 + cc) * R + r0 + u * 2] = o;
  }
}

// ---------------- GEMM1: 256x288, grid EXACTLY 256, 12 waves, minimal-sync ----------------
// r7 geometry (2M x 6N waves, per-wave 128x48, dbuf-2 136 KB) + r5 schedule:
// per K-tile: {vmcnt(0); barrier; burst-stage 6 instrs for t+1; sched_barrier;
// 22 ds_reads + 48 MFMA, NO inner barriers}. Single-barrier is race-free: a wave
// reaches the next tile-top barrier only after MFMAs consumed all its reads of the
// buffer staged next. Drain ~free (loads aged a full K-tile ~6000 cyc).
template<int BIAS>
__global__ __launch_bounds__(768, 3)
void gemm12w(const bf16* __restrict__ A, const bf16* __restrict__ BT,
             const float* __restrict__ bias, bf16* __restrict__ Cout,
             int M, int N, int K) {
  __shared__ __align__(16) bf16 Asb[2][256 * 64];
  __shared__ __align__(16) bf16 Bsb[2][288 * 64];

  const int tid  = threadIdx.x;
  const int lane = tid & 63;
  const int wid  = tid >> 6;          // 0..11
  const int wm   = wid / 6;           // 0..1 -> rows wm*128..
  const int wn   = wid % 6;           // 0..5 -> cols wn*48..
  const int lr   = lane & 15;
  const int lg   = lane >> 4;

  const int bm = (blockIdx.x & 7) * 256;   // XCD x owns one M-strip
  const int bn = (blockIdx.x >> 3) * 288;

  const int lrow = lane >> 3;
  const int csrc = ((lane & 7) ^ lrow) * 8;
  const bf16* Abase = A  + (size_t)(bm + lrow) * K + csrc;
  const bf16* Bbase = BT + (size_t)(bn + lrow) * K + csrc;

#define STG12(b, u, i) do {                                                       \
    const int L_ = wid + 12 * (i);                                                \
    if (L_ < 32)      GLOAD_LDS16(Abase + (size_t)(8 * L_) * K + (size_t)(u) * 64,\
                                  &Asb[b][L_ * 512]);                             \
    else if (L_ < 68) GLOAD_LDS16(Bbase + (size_t)(8 * (L_ - 32)) * K + (size_t)(u) * 64, \
                                  &Bsb[b][(L_ - 32) * 512]);                      \
  } while (0)
#define RA12(b, m, kk) (*(const short8*)(&Asb[b][(wm * 128 + (m) * 16 + lr) * 64 \
                          + ((((kk) * 4 + lg)) ^ (lr & 7)) * 8]))
#define RB12(b, n, kk) (*(const short8*)(&Bsb[b][(wn * 48 + (n) * 16 + lr) * 64 \
                          + ((((kk) * 4 + lg)) ^ (lr & 7)) * 8]))

  f32x4 acc[8][3] = {};
  const int NT = K >> 6;   // 48

  #pragma unroll
  for (int i = 0; i < 6; ++i) STG12(0, 0, i);

  for (int t = 0; t < NT; ++t) {
    const int c = t & 1, nc = c ^ 1;
    const bool pf = (t + 1) < NT;
    short8 a[4], b[3];

    asm volatile("s_waitcnt vmcnt(0)" ::: "memory");
    __builtin_amdgcn_s_barrier();

    if (pf) {
      STG12(nc, t + 1, 0); STG12(nc, t + 1, 1); STG12(nc, t + 1, 2);
      STG12(nc, t + 1, 3); STG12(nc, t + 1, 4); STG12(nc, t + 1, 5);
    }
    __builtin_amdgcn_sched_barrier(0);

    // kk0 x m0-3
    b[0] = RB12(c, 0, 0); b[1] = RB12(c, 1, 0); b[2] = RB12(c, 2, 0);
    a[0] = RA12(c, 0, 0); a[1] = RA12(c, 1, 0); a[2] = RA12(c, 2, 0); a[3] = RA12(c, 3, 0);
    #pragma unroll
    for (int n = 0; n < 3; ++n)
      #pragma unroll
      for (int m = 0; m < 4; ++m) acc[m][n] = mfma_16x16x32(a[m], b[n], acc[m][n]);

    // kk0 x m4-7
    a[0] = RA12(c, 4, 0); a[1] = RA12(c, 5, 0); a[2] = RA12(c, 6, 0); a[3] = RA12(c, 7, 0);
    #pragma unroll
    for (int n = 0; n < 3; ++n)
      #pragma unroll
      for (int m = 0; m < 4; ++m) acc[4 + m][n] = mfma_16x16x32(a[m], b[n], acc[4 + m][n]);

    // kk1 x m0-3
    b[0] = RB12(c, 0, 1); b[1] = RB12(c, 1, 1); b[2] = RB12(c, 2, 1);
    a[0] = RA12(c, 0, 1); a[1] = RA12(c, 1, 1); a[2] = RA12(c, 2, 1); a[3] = RA12(c, 3, 1);
    #pragma unroll
    for (int n = 0; n < 3; ++n)
      #pragma unroll
      for (int m = 0; m < 4; ++m) acc[m][n] = mfma_16x16x32(a[m], b[n], acc[m][n]);

    // kk1 x m4-7
    a[0] = RA12(c, 4, 1); a[1] = RA12(c, 5, 1); a[2] = RA12(c, 6, 1); a[3] = RA12(c, 7, 1);
    #pragma unroll
    for (int n = 0; n < 3; ++n)
      #pragma unroll
      for (int m = 0; m < 4; ++m) acc[4 + m][n] = mfma_16x16x32(a[m], b[n], acc[4 + m][n]);
  }
#undef STG12
#undef RA12
#undef RB12

  const int row0 = bm + wm * 128 + lg * 4;
  const int col0 = bn + wn * 48 + lr;
  #pragma unroll
  for (int n = 0; n < 3; ++n) {
    const int col = col0 + n * 16;
    const float bv = BIAS ? bias[col] : 0.0f;
    #pragma unroll
    for (int m = 0; m < 8; ++m)
      #pragma unroll
      for (int r = 0; r < 4; ++r)
        Cout[(size_t)(row0 + m * 16 + r) * N + col] = __float2bfloat16(acc[m][n][r] + bv);
  }
}

// ---------------- GEMM2: 128x192, grid EXACTLY 256 (16x16), 8 waves, minimal-sync ----------------
__global__ __launch_bounds__(512, 2)
void gemm8w(const bf16* __restrict__ A, const bf16* __restrict__ BT,
            float* __restrict__ Cout, int M, int N, int K) {
  __shared__ __align__(16) bf16 Asb[2][128 * 64];
  __shared__ __align__(16) bf16 Bsb[2][192 * 64];

  const int tid  = threadIdx.x;
  const int lane = tid & 63;
  const int wid  = tid >> 6;          // 0..7
  const int wm   = wid >> 2;          // 0..1 -> rows wm*64..
  const int wn   = wid & 3;           // 0..3 -> cols wn*48..
  const int lr   = lane & 15;
  const int lg   = lane >> 4;

  const int bm = (2 * (blockIdx.x & 7) + ((blockIdx.x >> 3) & 1)) * 128;
  const int bn = (blockIdx.x >> 4) * 192;

  const int lrow = lane >> 3;
  const int csrc = ((lane & 7) ^ lrow) * 8;
  const bf16* Abase = A  + (size_t)(bm + lrow) * K + csrc;
  const bf16* Bbase = BT + (size_t)(bn + lrow) * K + csrc;

#define STG8(b, u, i) do {                                                        \
    const int L_ = wid + 8 * (i);                                                 \
    if (L_ < 16)      GLOAD_LDS16(Abase + (size_t)(8 * L_) * K + (size_t)(u) * 64,\
                                  &Asb[b][L_ * 512]);                             \
    else              GLOAD_LDS16(Bbase + (size_t)(8 * (L_ - 16)) * K + (size_t)(u) * 64, \
                                  &Bsb[b][(L_ - 16) * 512]);                      \
  } while (0)
#define RA8(b, m, kk) (*(const short8*)(&Asb[b][(wm * 64 + (m) * 16 + lr) * 64 \
                          + ((((kk) * 4 + lg)) ^ (lr & 7)) * 8]))
#define RB8(b, n, kk) (*(const short8*)(&Bsb[b][(wn * 48 + (n) * 16 + lr) * 64 \
                          + ((((kk) * 4 + lg)) ^ (lr & 7)) * 8]))

  f32x4 acc[4][3] = {};
  const int NT = K >> 6;   // 48

  #pragma unroll
  for (int i = 0; i < 5; ++i) STG8(0, 0, i);

  for (int t = 0; t < NT; ++t) {
    const int c = t & 1, nc = c ^ 1;
    const bool pf = (t + 1) < NT;
    short8 a[4], b[3];

    asm volatile("s_waitcnt vmcnt(0)" ::: "memory");
    __builtin_amdgcn_s_barrier();

    if (pf) {
      STG8(nc, t + 1, 0); STG8(nc, t + 1, 1); STG8(nc, t + 1, 2);
      STG8(nc, t + 1, 3); STG8(nc, t + 1, 4);
    }
    __builtin_amdgcn_sched_barrier(0);

    b[0] = RB8(c, 0, 0); b[1] = RB8(c, 1, 0); b[2] = RB8(c, 2, 0);
    a[0] = RA8(c, 0, 0); a[1] = RA8(c, 1, 0); a[2] = RA8(c, 2, 0); a[3] = RA8(c, 3, 0);
    #pragma unroll
    for (int n = 0; n < 3; ++n)
      #pragma unroll
      for (int m = 0; m < 4; ++m) acc[m][n] = mfma_16x16x32(a[m], b[n], acc[m][n]);

    b[0] = RB8(c, 0, 1); b[1] = RB8(c, 1, 1); b[2] = RB8(c, 2, 1);
    a[0] = RA8(c, 0, 1); a[1] = RA8(c, 1, 1); a[2] = RA8(c, 2, 1); a[3] = RA8(c, 3, 1);
    #pragma unroll
    for (int n = 0; n < 3; ++n)
      #pragma unroll
      for (int m = 0; m < 4; ++m) acc[m][n] = mfma_16x16x32(a[m], b[n], acc[m][n]);
  }
#undef STG8
#undef RA8
#undef RB8

  const int row0 = bm + wm * 64 + lg * 4;
  const int col0 = bn + wn * 48 + lr;
  #pragma unroll
  for (int n = 0; n < 3; ++n) {
    const int col = col0 + n * 16;
    #pragma unroll
    for (int m = 0; m < 4; ++m)
      #pragma unroll
      for (int r = 0; r < 4; ++r)
        Cout[(size_t)(row0 + m * 16 + r) * N + col] = acc[m][n][r];
  }
}

// ---------------- RMSNorm over q,k head rows (128 elems), one wave per row ----------------
__global__ __launch_bounds__(256)
void rmsnorm_qk(bf16* __restrict__ qkv, const float* __restrict__ qw,
                const float* __restrict__ kw) {
  const int row  = blockIdx.x * 4 + (threadIdx.x >> 6);
  const int lane = threadIdx.x & 63;
  const int token = row / 48;
  const int rem   = row - token * 48;
  const int which = rem / 24;
  const int head  = rem - which * 24;
  bf16* p = qkv + (long)token * QKVN + which * HID + head * HD;
  const float a = __bfloat162float(p[lane * 2]);
  const float b = __bfloat162float(p[lane * 2 + 1]);
  float ss = a * a + b * b;
  #pragma unroll
  for (int mask = 32; mask >= 1; mask >>= 1) ss += __shfl_xor(ss, mask);
  const float inv = rsqrtf(ss * (1.0f / 128.0f) + 1e-6f);
  const float* w = which ? kw : qw;
  p[lane * 2]     = __float2bfloat16(a * inv * w[lane * 2]);
  p[lane * 2 + 1] = __float2bfloat16(b * inv * w[lane * 2 + 1]);
}

// ---------------- flash attention: r3 structure + T14 async-STAGE ----------------
// Loads for tile t+1 are issued right after tile t's LDS-write barrier, so their
// L2/L3 latency hides under QK+softmax+PV. Registers are consumed by ds_write
// before the overwriting loads issue (in-order per wave) -> no rotation needed.
__global__ __launch_bounds__(256, 2)
void attn_kernel(const bf16* __restrict__ qkv, bf16* __restrict__ ctx) {
  const int head = blockIdx.y;
  const int qb   = blockIdx.x;
  const int tid  = threadIdx.x;
  const int lane = tid & 63;
  const int wid  = tid >> 6;
  const int lr   = lane & 15;
  const int lg   = lane >> 4;

  __shared__ __align__(16) unsigned char Ksb[64 * 256];
  __shared__ __align__(16) unsigned char Vsb[128 * 128];
  __shared__ __align__(16) unsigned short Ps[4][16 * 72];

  const int qrow0 = qb * 64 + wid * 16;
  short8 qf[4];
  #pragma unroll
  for (int kt = 0; kt < 4; ++kt)
    qf[kt] = *(const short8*)(qkv + (long)(qrow0 + lr) * QKVN + head * HD + kt * 32 + lg * 8);

  f32x4 oacc[8] = {};
  float mrun[4], lrun[4];
  #pragma unroll
  for (int r = 0; r < 4; ++r) { mrun[r] = -1e30f; lrun[r] = 0.0f; }

  const float scale = 0.088388347648318447f;   // 1/sqrt(128)

  // per-thread staging geometry (compile-time per j)
  const int stok = tid >> 4;
  const int sdc  = tid & 15;

  // prologue: load tile 0
  short8 kreg[4], vreg[4];
  #pragma unroll
  for (int j = 0; j < 4; ++j) {
    const int tok = stok + (j & 1) * 16 + (j >> 1) * 32;   // any bijective cover of 64x16 chunks
    const int dc  = sdc;
    kreg[j] = *(const short8*)(qkv + (long)tok * QKVN + HID     + head * HD + dc * 8);
    vreg[j] = *(const short8*)(qkv + (long)tok * QKVN + 2 * HID + head * HD + dc * 8);
  }

  for (int t = 0; t < SEQ / 64; ++t) {
    __syncthreads();   // prior tile's LDS reads complete
    #pragma unroll
    for (int j = 0; j < 4; ++j) {
      const int tok = stok + (j & 1) * 16 + (j >> 1) * 32;
      const int dc  = sdc;
      *(short8*)(Ksb + ((tok * 256 + dc * 16) ^ ((tok & 7) << 4))) = kreg[j];
      const int dg = dc >> 1, h = dc & 1, kg = tok >> 2, kr = tok & 3;
      const int pos = (kg & 8) | ((kg & 1) << 2) | ((kg >> 1) & 3);
      *(short8*)(Vsb + (dg * 16 + pos) * 128 + kr * 32 + h * 16) = vreg[j];
    }
    __syncthreads();

    // T14: issue next tile's loads now; consumed at next iteration's write
    if (t + 1 < SEQ / 64) {
      const int kv1 = (t + 1) * 64;
      #pragma unroll
      for (int j = 0; j < 4; ++j) {
        const int tok = kv1 + stok + (j & 1) * 16 + (j >> 1) * 32;
        kreg[j] = *(const short8*)(qkv + (long)tok * QKVN + HID     + head * HD + sdc * 8);
        vreg[j] = *(const short8*)(qkv + (long)tok * QKVN + 2 * HID + head * HD + sdc * 8);
      }
      __builtin_amdgcn_sched_barrier(0);
    }

    f32x4 s[4];
    __builtin_amdgcn_s_setprio(1);
    #pragma unroll
    for (int ct = 0; ct < 4; ++ct) {
      f32x4 a = {};
      #pragma unroll
      for (int kt = 0; kt < 4; ++kt) {
        short8 kb = *(const short8*)(Ksb +
            ((((ct * 16 + lr) * 256) + kt * 64 + lg * 16) ^ ((lr & 7) << 4)));
        a = mfma_16x16x32(qf[kt], kb, a);
      }
      s[ct] = a;
    }
    __builtin_amdgcn_s_setprio(0);

    #pragma unroll
    for (int r = 0; r < 4; ++r) {
      float pm = fmaxf(fmaxf(s[0][r], s[1][r]), fmaxf(s[2][r], s[3][r]));
      #pragma unroll
      for (int mask = 1; mask <= 8; mask <<= 1) pm = fmaxf(pm, __shfl_xor(pm, mask));
      pm *= scale;
      const float mnew = fmaxf(mrun[r], pm);
      const float corr = __expf(mrun[r] - mnew);
      float psum = 0.0f;
      #pragma unroll
      for (int ct = 0; ct < 4; ++ct) {
        const float p = __expf(s[ct][r] * scale - mnew);
        psum += p;
        bf16 pb = __float2bfloat16(p);
        Ps[wid][(lg * 4 + r) * 72 + ct * 16 + lr] = *(unsigned short*)&pb;
      }
      #pragma unroll
      for (int mask = 1; mask <= 8; mask <<= 1) psum += __shfl_xor(psum, mask);
      lrun[r] = lrun[r] * corr + psum;
      mrun[r] = mnew;
      #pragma unroll
      for (int dt = 0; dt < 8; ++dt) oacc[dt][r] *= corr;
    }

    short8 pa[2];
    #pragma unroll
    for (int kt = 0; kt < 2; ++kt)
      pa[kt] = *(const short8*)&Ps[wid][lr * 72 + kt * 32 + lg * 8];

    lds_cchar* vb0 = (lds_cchar*)Vsb + lane * 8;
    __builtin_amdgcn_s_setprio(1);
    #pragma unroll
    for (int dt = 0; dt < 8; ++dt) {
      lds_cchar* pd = vb0 + dt * 2048;
      ull r0, r1, r2, r3;
      asm volatile("ds_read_b64_tr_b16 %0, %1 offset:0"    : "=v"(r0) : "v"(pd));
      asm volatile("ds_read_b64_tr_b16 %0, %1 offset:512"  : "=v"(r1) : "v"(pd));
      asm volatile("ds_read_b64_tr_b16 %0, %1 offset:1024" : "=v"(r2) : "v"(pd));
      asm volatile("ds_read_b64_tr_b16 %0, %1 offset:1536" : "=v"(r3) : "v"(pd));
      asm volatile("s_waitcnt lgkmcnt(0)" ::: "memory");
      __builtin_amdgcn_sched_barrier(0);
      short8 vb_0, vb_1;
      ((ull*)&vb_0)[0] = r0; ((ull*)&vb_0)[1] = r1;
      ((ull*)&vb_1)[0] = r2; ((ull*)&vb_1)[1] = r3;
      oacc[dt] = mfma_16x16x32(pa[0], vb_0, oacc[dt]);
      oacc[dt] = mfma_16x16x32(pa[1], vb_1, oacc[dt]);
    }
    __builtin_amdgcn_s_setprio(0);
  }

  #pragma unroll
  for (int r = 0; r < 4; ++r) {
    const float inv = 1.0f / lrun[r];
    const long tok = qrow0 + lg * 4 + r;
    #pragma unroll
    for (int dt = 0; dt < 8; ++dt)
      ctx[tok * HID + head * HD + dt * 16 + lr] = __float2bfloat16(oacc[dt][r] * inv);
  }
}

extern "C" void kernel_launch(void* const* d_in, const int* in_sizes, int n_in,
                              void* d_out, int out_size, void* d_ws, size_t ws_size,
                              hipStream_t stream) {
  (void)in_sizes; (void)n_in; (void)out_size; (void)ws_size;
  const float* x     = (const float*)d_in[0];
  const float* Wqkv  = (const float*)d_in[1];
  const float* bqkv  = (const float*)d_in[2];
  const float* Wproj = (const float*)d_in[3];
  const float* qw    = (const float*)d_in[4];
  const float* kw    = (const float*)d_in[5];

  char* ws = (char*)d_ws;
  bf16* xb     = (bf16*)ws;                     // 2048x3072 bf16
  bf16* WqkvT  = (bf16*)(ws + 12582912);        // 9216x3072 bf16
  bf16* WprojT = (bf16*)(ws + 69206016);        // 3072x3072 bf16
  bf16* qkv    = (bf16*)(ws + 88080384);        // 2048x9216 bf16
  bf16* ctx    = xb;                            // xb dead after GEMM1

  cvt_f32_bf16_vec<<<(SEQ * HID / 4 + 255) / 256, 256, 0, stream>>>(x, xb, SEQ * HID / 4);
  transpose_cvt64<<<dim3(QKVN / 64, HID / 32), 256, 0, stream>>>(Wqkv, WqkvT, HID, QKVN);
  transpose_cvt64<<<dim3(HID / 64, HID / 32), 256, 0, stream>>>(Wproj, WprojT, HID, HID);

  gemm12w<1><<<256, 768, 0, stream>>>(xb, WqkvT, bqkv, qkv, SEQ, QKVN, HID);

  rmsnorm_qk<<<SEQ * 48 / 4, 256, 0, stream>>>(qkv, qw, kw);

  attn_kernel<<<dim3(SEQ / 64, NH), 256, 0, stream>>>(qkv, ctx);

  gemm8w<<<256, 512, 0, stream>>>(ctx, WprojT, (float*)d_out, SEQ, HID, HID);
}

// Round 9
// 328.790 us; speedup vs baseline: 1.4100x; 1.0816x over previous
//
#include <hip/hip_runtime.h>
#include <hip/hip_bf16.h>

using bf16 = __hip_bfloat16;
typedef __attribute__((ext_vector_type(8))) short short8;   // 8 x bf16 fragment (4 VGPRs)
typedef __attribute__((ext_vector_type(4))) float f32x4;
typedef unsigned long long ull;

static constexpr int SEQ  = 2048;
static constexpr int HID  = 3072;
static constexpr int NH   = 24;
static constexpr int HD   = 128;
static constexpr int QKVN = 9216;

__device__ __forceinline__ f32x4 mfma_16x16x32(short8 a, short8 b, f32x4 c) {
  return __builtin_amdgcn_mfma_f32_16x16x32_bf16(a, b, c, 0, 0, 0);
}

#define GLOAD_LDS16(g, l) __builtin_amdgcn_global_load_lds(                 \
    (const __attribute__((address_space(1))) void*)(g),                    \
    (__attribute__((address_space(3))) void*)(l), 16, 0, 0)

typedef __attribute__((address_space(3))) const unsigned char lds_cchar;

__device__ __forceinline__ unsigned pack_bf16(float lo, float hi) {
  bf16 l = __float2bfloat16(lo), h = __float2bfloat16(hi);
  return (unsigned)*(unsigned short*)&l | ((unsigned)*(unsigned short*)&h << 16);
}

// ---------------- fp32 -> bf16 vectorized convert ----------------
__global__ __launch_bounds__(256)
void cvt_f32_bf16_vec(const float* __restrict__ src, bf16* __restrict__ dst, int n4) {
  int i = blockIdx.x * 256 + threadIdx.x;
  if (i >= n4) return;
  float4 v = ((const float4*)src)[i];
  ushort4 o;
  bf16 t0 = __float2bfloat16(v.x); o.x = *(unsigned short*)&t0;
  bf16 t1 = __float2bfloat16(v.y); o.y = *(unsigned short*)&t1;
  bf16 t2 = __float2bfloat16(v.z); o.z = *(unsigned short*)&t2;
  bf16 t3 = __float2bfloat16(v.w); o.w = *(unsigned short*)&t3;
  ((ushort4*)dst)[i] = o;
}

// ---------------- fp32 (R x C) -> bf16 transposed (C x R), vectorized stores ----------------
__global__ __launch_bounds__(256)
void transpose_cvt64(const float* __restrict__ src, bf16* __restrict__ dst, int R, int C) {
  __shared__ float tile[32][65];
  const int c0 = blockIdx.x * 64, r0 = blockIdx.y * 32;
  const int lc = threadIdx.x & 63, lt = threadIdx.x >> 6;
  #pragma unroll
  for (int i = 0; i < 8; ++i)
    tile[lt + i * 4][lc] = src[(size_t)(r0 + lt + i * 4) * C + c0 + lc];
  __syncthreads();
  const int u = threadIdx.x & 15, dr = threadIdx.x >> 4;
  #pragma unroll
  for (int j = 0; j < 4; ++j) {
    const int cc = dr + j * 16;
    bf16 x0 = __float2bfloat16(tile[u * 2][cc]);
    bf16 x1 = __float2bfloat16(tile[u * 2 + 1][cc]);
    ushort2 o;
    o.x = *(unsigned short*)&x0; o.y = *(unsigned short*)&x1;
    *(ushort2*)&dst[(size_t)(c0 + cc) * R + r0 + u * 2] = o;
  }
}

// ---------------- GEMM1: 256x288, grid EXACTLY 256, 12 waves, minimal-sync (r8, proven) ----------------
template<int BIAS>
__global__ __launch_bounds__(768, 3)
void gemm12w(const bf16* __restrict__ A, const bf16* __restrict__ BT,
             const float* __restrict__ bias, bf16* __restrict__ Cout,
             int M, int N, int K) {
  __shared__ __align__(16) bf16 Asb[2][256 * 64];
  __shared__ __align__(16) bf16 Bsb[2][288 * 64];

  const int tid  = threadIdx.x;
  const int lane = tid & 63;
  const int wid  = tid >> 6;          // 0..11
  const int wm   = wid / 6;           // 0..1 -> rows wm*128..
  const int wn   = wid % 6;           // 0..5 -> cols wn*48..
  const int lr   = lane & 15;
  const int lg   = lane >> 4;

  const int bm = (blockIdx.x & 7) * 256;   // XCD x owns one M-strip
  const int bn = (blockIdx.x >> 3) * 288;

  const int lrow = lane >> 3;
  const int csrc = ((lane & 7) ^ lrow) * 8;
  const bf16* Abase = A  + (size_t)(bm + lrow) * K + csrc;
  const bf16* Bbase = BT + (size_t)(bn + lrow) * K + csrc;

#define STG12(b, u, i) do {                                                       \
    const int L_ = wid + 12 * (i);                                                \
    if (L_ < 32)      GLOAD_LDS16(Abase + (size_t)(8 * L_) * K + (size_t)(u) * 64,\
                                  &Asb[b][L_ * 512]);                             \
    else if (L_ < 68) GLOAD_LDS16(Bbase + (size_t)(8 * (L_ - 32)) * K + (size_t)(u) * 64, \
                                  &Bsb[b][(L_ - 32) * 512]);                      \
  } while (0)
#define RA12(b, m, kk) (*(const short8*)(&Asb[b][(wm * 128 + (m) * 16 + lr) * 64 \
                          + ((((kk) * 4 + lg)) ^ (lr & 7)) * 8]))
#define RB12(b, n, kk) (*(const short8*)(&Bsb[b][(wn * 48 + (n) * 16 + lr) * 64 \
                          + ((((kk) * 4 + lg)) ^ (lr & 7)) * 8]))

  f32x4 acc[8][3] = {};
  const int NT = K >> 6;   // 48

  #pragma unroll
  for (int i = 0; i < 6; ++i) STG12(0, 0, i);

  for (int t = 0; t < NT; ++t) {
    const int c = t & 1, nc = c ^ 1;
    const bool pf = (t + 1) < NT;
    short8 a[4], b[3];

    asm volatile("s_waitcnt vmcnt(0)" ::: "memory");
    __builtin_amdgcn_s_barrier();

    if (pf) {
      STG12(nc, t + 1, 0); STG12(nc, t + 1, 1); STG12(nc, t + 1, 2);
      STG12(nc, t + 1, 3); STG12(nc, t + 1, 4); STG12(nc, t + 1, 5);
    }
    __builtin_amdgcn_sched_barrier(0);

    // kk0 x m0-3
    b[0] = RB12(c, 0, 0); b[1] = RB12(c, 1, 0); b[2] = RB12(c, 2, 0);
    a[0] = RA12(c, 0, 0); a[1] = RA12(c, 1, 0); a[2] = RA12(c, 2, 0); a[3] = RA12(c, 3, 0);
    #pragma unroll
    for (int n = 0; n < 3; ++n)
      #pragma unroll
      for (int m = 0; m < 4; ++m) acc[m][n] = mfma_16x16x32(a[m], b[n], acc[m][n]);

    // kk0 x m4-7
    a[0] = RA12(c, 4, 0); a[1] = RA12(c, 5, 0); a[2] = RA12(c, 6, 0); a[3] = RA12(c, 7, 0);
    #pragma unroll
    for (int n = 0; n < 3; ++n)
      #pragma unroll
      for (int m = 0; m < 4; ++m) acc[4 + m][n] = mfma_16x16x32(a[m], b[n], acc[4 + m][n]);

    // kk1 x m0-3
    b[0] = RB12(c, 0, 1); b[1] = RB12(c, 1, 1); b[2] = RB12(c, 2, 1);
    a[0] = RA12(c, 0, 1); a[1] = RA12(c, 1, 1); a[2] = RA12(c, 2, 1); a[3] = RA12(c, 3, 1);
    #pragma unroll
    for (int n = 0; n < 3; ++n)
      #pragma unroll
      for (int m = 0; m < 4; ++m) acc[m][n] = mfma_16x16x32(a[m], b[n], acc[m][n]);

    // kk1 x m4-7
    a[0] = RA12(c, 4, 1); a[1] = RA12(c, 5, 1); a[2] = RA12(c, 6, 1); a[3] = RA12(c, 7, 1);
    #pragma unroll
    for (int n = 0; n < 3; ++n)
      #pragma unroll
      for (int m = 0; m < 4; ++m) acc[4 + m][n] = mfma_16x16x32(a[m], b[n], acc[4 + m][n]);
  }
#undef STG12
#undef RA12
#undef RB12

  const int row0 = bm + wm * 128 + lg * 4;
  const int col0 = bn + wn * 48 + lr;
  #pragma unroll
  for (int n = 0; n < 3; ++n) {
    const int col = col0 + n * 16;
    const float bv = BIAS ? bias[col] : 0.0f;
    #pragma unroll
    for (int m = 0; m < 8; ++m)
      #pragma unroll
      for (int r = 0; r < 4; ++r)
        Cout[(size_t)(row0 + m * 16 + r) * N + col] = __float2bfloat16(acc[m][n][r] + bv);
  }
}

// ---------------- GEMM2: 128x192, grid EXACTLY 256 (16x16), 8 waves, minimal-sync ----------------
__global__ __launch_bounds__(512, 2)
void gemm8w(const bf16* __restrict__ A, const bf16* __restrict__ BT,
            float* __restrict__ Cout, int M, int N, int K) {
  __shared__ __align__(16) bf16 Asb[2][128 * 64];
  __shared__ __align__(16) bf16 Bsb[2][192 * 64];

  const int tid  = threadIdx.x;
  const int lane = tid & 63;
  const int wid  = tid >> 6;          // 0..7
  const int wm   = wid >> 2;          // 0..1 -> rows wm*64..
  const int wn   = wid & 3;           // 0..3 -> cols wn*48..
  const int lr   = lane & 15;
  const int lg   = lane >> 4;

  const int bm = (2 * (blockIdx.x & 7) + ((blockIdx.x >> 3) & 1)) * 128;
  const int bn = (blockIdx.x >> 4) * 192;

  const int lrow = lane >> 3;
  const int csrc = ((lane & 7) ^ lrow) * 8;
  const bf16* Abase = A  + (size_t)(bm + lrow) * K + csrc;
  const bf16* Bbase = BT + (size_t)(bn + lrow) * K + csrc;

#define STG8(b, u, i) do {                                                        \
    const int L_ = wid + 8 * (i);                                                 \
    if (L_ < 16)      GLOAD_LDS16(Abase + (size_t)(8 * L_) * K + (size_t)(u) * 64,\
                                  &Asb[b][L_ * 512]);                             \
    else              GLOAD_LDS16(Bbase + (size_t)(8 * (L_ - 16)) * K + (size_t)(u) * 64, \
                                  &Bsb[b][(L_ - 16) * 512]);                      \
  } while (0)
#define RA8(b, m, kk) (*(const short8*)(&Asb[b][(wm * 64 + (m) * 16 + lr) * 64 \
                          + ((((kk) * 4 + lg)) ^ (lr & 7)) * 8]))
#define RB8(b, n, kk) (*(const short8*)(&Bsb[b][(wn * 48 + (n) * 16 + lr) * 64 \
                          + ((((kk) * 4 + lg)) ^ (lr & 7)) * 8]))

  f32x4 acc[4][3] = {};
  const int NT = K >> 6;   // 48

  #pragma unroll
  for (int i = 0; i < 5; ++i) STG8(0, 0, i);

  for (int t = 0; t < NT; ++t) {
    const int c = t & 1, nc = c ^ 1;
    const bool pf = (t + 1) < NT;
    short8 a[4], b[3];

    asm volatile("s_waitcnt vmcnt(0)" ::: "memory");
    __builtin_amdgcn_s_barrier();

    if (pf) {
      STG8(nc, t + 1, 0); STG8(nc, t + 1, 1); STG8(nc, t + 1, 2);
      STG8(nc, t + 1, 3); STG8(nc, t + 1, 4);
    }
    __builtin_amdgcn_sched_barrier(0);

    b[0] = RB8(c, 0, 0); b[1] = RB8(c, 1, 0); b[2] = RB8(c, 2, 0);
    a[0] = RA8(c, 0, 0); a[1] = RA8(c, 1, 0); a[2] = RA8(c, 2, 0); a[3] = RA8(c, 3, 0);
    #pragma unroll
    for (int n = 0; n < 3; ++n)
      #pragma unroll
      for (int m = 0; m < 4; ++m) acc[m][n] = mfma_16x16x32(a[m], b[n], acc[m][n]);

    b[0] = RB8(c, 0, 1); b[1] = RB8(c, 1, 1); b[2] = RB8(c, 2, 1);
    a[0] = RA8(c, 0, 1); a[1] = RA8(c, 1, 1); a[2] = RA8(c, 2, 1); a[3] = RA8(c, 3, 1);
    #pragma unroll
    for (int n = 0; n < 3; ++n)
      #pragma unroll
      for (int m = 0; m < 4; ++m) acc[m][n] = mfma_16x16x32(a[m], b[n], acc[m][n]);
  }
#undef STG8
#undef RA8
#undef RB8

  const int row0 = bm + wm * 64 + lg * 4;
  const int col0 = bn + wn * 48 + lr;
  #pragma unroll
  for (int n = 0; n < 3; ++n) {
    const int col = col0 + n * 16;
    #pragma unroll
    for (int m = 0; m < 4; ++m)
      #pragma unroll
      for (int r = 0; r < 4; ++r)
        Cout[(size_t)(row0 + m * 16 + r) * N + col] = acc[m][n][r];
  }
}

// ---------------- RMSNorm over q,k head rows (128 elems), one wave per row ----------------
__global__ __launch_bounds__(256)
void rmsnorm_qk(bf16* __restrict__ qkv, const float* __restrict__ qw,
                const float* __restrict__ kw) {
  const int row  = blockIdx.x * 4 + (threadIdx.x >> 6);
  const int lane = threadIdx.x & 63;
  const int token = row / 48;
  const int rem   = row - token * 48;
  const int which = rem / 24;
  const int head  = rem - which * 24;
  bf16* p = qkv + (long)token * QKVN + which * HID + head * HD;
  const float a = __bfloat162float(p[lane * 2]);
  const float b = __bfloat162float(p[lane * 2 + 1]);
  float ss = a * a + b * b;
  #pragma unroll
  for (int mask = 32; mask >= 1; mask >>= 1) ss += __shfl_xor(ss, mask);
  const float inv = rsqrtf(ss * (1.0f / 128.0f) + 1e-6f);
  const float* w = which ? kw : qw;
  p[lane * 2]     = __float2bfloat16(a * inv * w[lane * 2]);
  p[lane * 2 + 1] = __float2bfloat16(b * inv * w[lane * 2 + 1]);
}

// ---------------- flash attention: swapped QK^T, in-lane softmax ----------------
// S^T = mfma(K_frag, Q_frag): lane holds S[q=lr][key=ct*16+lg*4+r] -> row stats are
// per-lane (q=lr): in-lane max + 2 shfls (was 32 shfls); per-lane partial sum,
// cross-lane reduced once in the epilogue. P stored as 4x ds_write_b64 (packed
// bf16 pairs) at the SAME P[q][key] semantics -> pa/PV path unchanged.
__global__ __launch_bounds__(256, 2)
void attn_kernel(const bf16* __restrict__ qkv, bf16* __restrict__ ctx) {
  const int head = blockIdx.y;
  const int qb   = blockIdx.x;
  const int tid  = threadIdx.x;
  const int lane = tid & 63;
  const int wid  = tid >> 6;
  const int lr   = lane & 15;
  const int lg   = lane >> 4;

  __shared__ __align__(16) unsigned char Ksb[64 * 256];
  __shared__ __align__(16) unsigned char Vsb[128 * 128];
  __shared__ __align__(16) unsigned short Ps[4][16 * 72];

  const int qrow0 = qb * 64 + wid * 16;
  short8 qf[4];
  #pragma unroll
  for (int kt = 0; kt < 4; ++kt)
    qf[kt] = *(const short8*)(qkv + (long)(qrow0 + lr) * QKVN + head * HD + kt * 32 + lg * 8);

  f32x4 oacc[8] = {};
  float mrun = -1e30f, lsum = 0.0f;   // per-lane stats for q-row = lr

  const float scale = 0.088388347648318447f;   // 1/sqrt(128)

  const int stok = tid >> 4;
  const int sdc  = tid & 15;

  short8 kreg[4], vreg[4];
  #pragma unroll
  for (int j = 0; j < 4; ++j) {
    const int tok = stok + (j & 1) * 16 + (j >> 1) * 32;
    kreg[j] = *(const short8*)(qkv + (long)tok * QKVN + HID     + head * HD + sdc * 8);
    vreg[j] = *(const short8*)(qkv + (long)tok * QKVN + 2 * HID + head * HD + sdc * 8);
  }

  for (int t = 0; t < SEQ / 64; ++t) {
    __syncthreads();
    #pragma unroll
    for (int j = 0; j < 4; ++j) {
      const int tok = stok + (j & 1) * 16 + (j >> 1) * 32;
      const int dc  = sdc;
      *(short8*)(Ksb + ((tok * 256 + dc * 16) ^ ((tok & 7) << 4))) = kreg[j];
      const int dg = dc >> 1, h = dc & 1, kg = tok >> 2, kr = tok & 3;
      const int pos = (kg & 8) | ((kg & 1) << 2) | ((kg >> 1) & 3);
      *(short8*)(Vsb + (dg * 16 + pos) * 128 + kr * 32 + h * 16) = vreg[j];
    }
    __syncthreads();

    // T14: issue next tile's loads under this tile's compute
    if (t + 1 < SEQ / 64) {
      const int kv1 = (t + 1) * 64;
      #pragma unroll
      for (int j = 0; j < 4; ++j) {
        const int tok = kv1 + stok + (j & 1) * 16 + (j >> 1) * 32;
        kreg[j] = *(const short8*)(qkv + (long)tok * QKVN + HID     + head * HD + sdc * 8);
        vreg[j] = *(const short8*)(qkv + (long)tok * QKVN + 2 * HID + head * HD + sdc * 8);
      }
      __builtin_amdgcn_sched_barrier(0);
    }

    // S^T = mfma(K, Q): st[ct][r] = S[q=lr][key=ct*16+lg*4+r]
    f32x4 st[4];
    __builtin_amdgcn_s_setprio(1);
    #pragma unroll
    for (int ct = 0; ct < 4; ++ct) {
      f32x4 a = {};
      #pragma unroll
      for (int kt = 0; kt < 4; ++kt) {
        short8 kb = *(const short8*)(Ksb +
            ((((ct * 16 + lr) * 256) + kt * 64 + lg * 16) ^ ((lr & 7) << 4)));
        a = mfma_16x16x32(kb, qf[kt], a);    // swapped operands
      }
      st[ct] = a;
    }
    __builtin_amdgcn_s_setprio(0);

    // in-lane softmax for q = lr over this lane's 16 keys
    float pm = st[0][0];
    #pragma unroll
    for (int ct = 0; ct < 4; ++ct)
      #pragma unroll
      for (int r = 0; r < 4; ++r) pm = fmaxf(pm, st[ct][r]);
    pm *= scale;
    pm = fmaxf(pm, __shfl_xor(pm, 16));
    pm = fmaxf(pm, __shfl_xor(pm, 32));
    const float mnew = fmaxf(mrun, pm);
    const float corr = __expf(mrun - mnew);
    mrun = mnew;

    float ps = 0.0f;
    #pragma unroll
    for (int ct = 0; ct < 4; ++ct) {
      const float p0 = __expf(st[ct][0] * scale - mnew);
      const float p1 = __expf(st[ct][1] * scale - mnew);
      const float p2 = __expf(st[ct][2] * scale - mnew);
      const float p3 = __expf(st[ct][3] * scale - mnew);
      ps += (p0 + p1) + (p2 + p3);
      uint2 w;
      w.x = pack_bf16(p0, p1);
      w.y = pack_bf16(p2, p3);
      *(uint2*)&Ps[wid][lr * 72 + ct * 16 + lg * 4] = w;   // P[q=lr][key=16ct+4lg..+3]
    }
    lsum = lsum * corr + ps;

    // rescale O (rows q = lg*4+r need corr from lane lg*4+r)
    #pragma unroll
    for (int r = 0; r < 4; ++r) {
      const float cr = __shfl(corr, lg * 4 + r);
      #pragma unroll
      for (int dt = 0; dt < 8; ++dt) oacc[dt][r] *= cr;
    }

    short8 pa[2];
    #pragma unroll
    for (int kt = 0; kt < 2; ++kt)
      pa[kt] = *(const short8*)&Ps[wid][lr * 72 + kt * 32 + lg * 8];

    lds_cchar* vb0 = (lds_cchar*)Vsb + lane * 8;
    __builtin_amdgcn_s_setprio(1);
    #pragma unroll
    for (int dt = 0; dt < 8; ++dt) {
      lds_cchar* pd = vb0 + dt * 2048;
      ull r0, r1, r2, r3;
      asm volatile("ds_read_b64_tr_b16 %0, %1 offset:0"    : "=v"(r0) : "v"(pd));
      asm volatile("ds_read_b64_tr_b16 %0, %1 offset:512"  : "=v"(r1) : "v"(pd));
      asm volatile("ds_read_b64_tr_b16 %0, %1 offset:1024" : "=v"(r2) : "v"(pd));
      asm volatile("ds_read_b64_tr_b16 %0, %1 offset:1536" : "=v"(r3) : "v"(pd));
      asm volatile("s_waitcnt lgkmcnt(0)" ::: "memory");
      __builtin_amdgcn_sched_barrier(0);
      short8 vb_0, vb_1;
      ((ull*)&vb_0)[0] = r0; ((ull*)&vb_0)[1] = r1;
      ((ull*)&vb_1)[0] = r2; ((ull*)&vb_1)[1] = r3;
      oacc[dt] = mfma_16x16x32(pa[0], vb_0, oacc[dt]);
      oacc[dt] = mfma_16x16x32(pa[1], vb_1, oacc[dt]);
    }
    __builtin_amdgcn_s_setprio(0);
  }

  // epilogue: reduce per-lane partial sums (q=lr), broadcast to O rows (q=lg*4+r)
  lsum += __shfl_xor(lsum, 16);
  lsum += __shfl_xor(lsum, 32);
  const float invl = 1.0f / lsum;
  #pragma unroll
  for (int r = 0; r < 4; ++r) {
    const float inv = __shfl(invl, lg * 4 + r);
    const long tok = qrow0 + lg * 4 + r;
    #pragma unroll
    for (int dt = 0; dt < 8; ++dt)
      ctx[tok * HID + head * HD + dt * 16 + lr] = __float2bfloat16(oacc[dt][r] * inv);
  }
}

extern "C" void kernel_launch(void* const* d_in, const int* in_sizes, int n_in,
                              void* d_out, int out_size, void* d_ws, size_t ws_size,
                              hipStream_t stream) {
  (void)in_sizes; (void)n_in; (void)out_size; (void)ws_size;
  const float* x     = (const float*)d_in[0];
  const float* Wqkv  = (const float*)d_in[1];
  const float* bqkv  = (const float*)d_in[2];
  const float* Wproj = (const float*)d_in[3];
  const float* qw    = (const float*)d_in[4];
  const float* kw    = (const float*)d_in[5];

  char* ws = (char*)d_ws;
  bf16* xb     = (bf16*)ws;                     // 2048x3072 bf16
  bf16* WqkvT  = (bf16*)(ws + 12582912);        // 9216x3072 bf16
  bf16* WprojT = (bf16*)(ws + 69206016);        // 3072x3072 bf16
  bf16* qkv    = (bf16*)(ws + 88080384);        // 2048x9216 bf16
  bf16* ctx    = xb;                            // xb dead after GEMM1

  cvt_f32_bf16_vec<<<(SEQ * HID / 4 + 255) / 256, 256, 0, stream>>>(x, xb, SEQ * HID / 4);
  transpose_cvt64<<<dim3(QKVN / 64, HID / 32), 256, 0, stream>>>(Wqkv, WqkvT, HID, QKVN);
  transpose_cvt64<<<dim3(HID / 64, HID / 32), 256, 0, stream>>>(Wproj, WprojT, HID, HID);

  gemm12w<1><<<256, 768, 0, stream>>>(xb, WqkvT, bqkv, qkv, SEQ, QKVN, HID);

  rmsnorm_qk<<<SEQ * 48 / 4, 256, 0, stream>>>(qkv, qw, kw);

  attn_kernel<<<dim3(SEQ / 64, NH), 256, 0, stream>>>(qkv, ctx);

  gemm8w<<<256, 512, 0, stream>>>(ctx, WprojT, (float*)d_out, SEQ, HID, HID);
}